// Round 5
// baseline (277.223 us; speedup 1.0000x reference)
//
#include <hip/hip_runtime.h>
#include <hip/hip_bf16.h>

#define IN_C 512
#define HID_C 128
#define OUT_C 16
#define TILE 1024      // destination nodes per tile (shift by 10)
#define KCH 4          // edge chunks per tile

typedef float f32x4 __attribute__((ext_vector_type(4)));
typedef int   i32x4 __attribute__((ext_vector_type(4)));

// ---------------------------------------------------------------------------
// K1: folded weights + bias const + zero deg.
//   Wc[o][k] = sum_h W2[o][h] * W1[h][k]   (16 x 512)
//   cconst[o] = b2[o] + sum_h b1[h] * W2[o][h]
// ---------------------------------------------------------------------------
__global__ void prep_kernel(const float* __restrict__ W1, const float* __restrict__ b1,
                            const float* __restrict__ W2, const float* __restrict__ b2,
                            float* __restrict__ Wc, float* __restrict__ cconst,
                            int* __restrict__ deg, int N) {
    if (blockIdx.x < 32) {
        int idx = blockIdx.x * 256 + threadIdx.x;   // 0 .. 8191
        int o = idx >> 9;
        int k = idx & 511;
        float s = 0.f;
#pragma unroll 8
        for (int h = 0; h < HID_C; ++h)
            s = fmaf(W2[o * HID_C + h], W1[h * IN_C + k], s);
        Wc[o * IN_C + k] = s;
    } else if (blockIdx.x == 32) {
        if (threadIdx.x < OUT_C) {
            int o = threadIdx.x;
            float s = b2[o];
            for (int h = 0; h < HID_C; ++h)
                s = fmaf(b1[h], W2[o * HID_C + h], s);
            cconst[o] = s;
        }
    } else {
        int n = (blockIdx.x - 33) * 256 + threadIdx.x;
        if (n < N) deg[n] = 0;
    }
}

// ---------------------------------------------------------------------------
// K2: LDS-binned degree histogram. Block (t,k): LDS hist of chunk k's cols
// falling in tile t, then coalesced global-atomic merge (196K atomics total).
// ---------------------------------------------------------------------------
__global__ __launch_bounds__(512) void hist_kernel(const int* __restrict__ ei,
                                                   int* __restrict__ deg, int E, int N) {
    __shared__ int hacc[TILE];
    const int t = blockIdx.x / KCH;
    const int k = blockIdx.x - t * KCH;
    for (int i = threadIdx.x; i < TILE; i += 512) hacc[i] = 0;
    __syncthreads();

    const int chunk = (((E + KCH - 1) / KCH) + 3) & ~3;   // multiple of 4
    const int beg = k * chunk;
    const int end = min(E, beg + chunk);
    const int* cols = ei + E;

    const int nv = (end > beg) ? (end - beg) >> 2 : 0;
    const i32x4* cv = (const i32x4*)(cols + beg);
    for (int i = threadIdx.x; i < nv; i += 512) {
        i32x4 c = cv[i];
#pragma unroll
        for (int j = 0; j < 4; ++j) {
            int cj = c[j];
            if ((cj >> 10) == t) atomicAdd(&hacc[cj & (TILE - 1)], 1);
        }
    }
    for (int e = beg + (nv << 2) + threadIdx.x; e < end; e += 512) {
        int cj = cols[e];
        if ((cj >> 10) == t) atomicAdd(&hacc[cj & (TILE - 1)], 1);
    }
    __syncthreads();
    const int lo = t * TILE;
    for (int i = threadIdx.x; i < TILE; i += 512) {
        int v = hacc[i];
        if (v && lo + i < N) atomicAdd(&deg[lo + i], v);
    }
}

// K3: dsq[n] = sqrt(deg[n])
__global__ void dsq_kernel(const int* __restrict__ deg, float* __restrict__ dsq, int N) {
    int n = blockIdx.x * 256 + threadIdx.x;
    if (n < N) dsq[n] = sqrtf((float)deg[n]);
}

// ---------------------------------------------------------------------------
// K4: h2p[r][o] = dsq[r] * (x[r] @ Wc^T)[o].  One wave per row; Wc in VGPRs.
// ---------------------------------------------------------------------------
__global__ __launch_bounds__(256, 2) void h2_kernel(const float* __restrict__ x,
                                                    const float* __restrict__ Wc,
                                                    const float* __restrict__ dsq,
                                                    float* __restrict__ h2p, int N) {
    const int lane = threadIdx.x & 63;
    const int gw = (blockIdx.x * 256 + threadIdx.x) >> 6;
    const int nw = (gridDim.x * 256) >> 6;

    f32x4 w0[16], w1[16];
#pragma unroll
    for (int o = 0; o < 16; ++o) {
        w0[o] = *(const f32x4*)(Wc + o * IN_C + 4 * lane);
        w1[o] = *(const f32x4*)(Wc + o * IN_C + 256 + 4 * lane);
    }

    for (int r = gw; r < N; r += nw) {
        const float dr = dsq[r];
        const f32x4 a0 = *(const f32x4*)(x + (size_t)r * IN_C + 4 * lane);
        const f32x4 a1 = *(const f32x4*)(x + (size_t)r * IN_C + 256 + 4 * lane);
        float p[16];
#pragma unroll
        for (int o = 0; o < 16; ++o) {
            float s = a0.x * w0[o].x;
            s = fmaf(a0.y, w0[o].y, s);
            s = fmaf(a0.z, w0[o].z, s);
            s = fmaf(a0.w, w0[o].w, s);
            s = fmaf(a1.x, w1[o].x, s);
            s = fmaf(a1.y, w1[o].y, s);
            s = fmaf(a1.z, w1[o].z, s);
            s = fmaf(a1.w, w1[o].w, s);
            p[o] = s;
        }
#define RSTEP(MASK, HALF)                                            \
        {                                                            \
            const bool hi = (lane & MASK) != 0;                      \
            _Pragma("unroll")                                        \
            for (int i = 0; i < HALF; ++i) {                         \
                float send = hi ? p[i] : p[i + HALF];                \
                float recv = __shfl_xor(send, MASK, 64);             \
                float keep = hi ? p[i + HALF] : p[i];                \
                p[i] = keep + recv;                                  \
            }                                                        \
        }
        RSTEP(1, 8)
        RSTEP(2, 4)
        RSTEP(4, 2)
        RSTEP(8, 1)
#undef RSTEP
        float v = p[0];
        v += __shfl_xor(v, 16, 64);
        v += __shfl_xor(v, 32, 64);
        if (lane < 16) {
            int o = ((lane & 1) << 3) | ((lane & 2) << 1) | ((lane & 4) >> 1) | ((lane & 8) >> 3);
            h2p[(size_t)r * 16 + o] = v * dr;
        }
    }
}

// ---------------------------------------------------------------------------
// K5: tile-scan. Block (t,k) scans chunk k's edges; for c in tile t,
// acc_lds[c & 1023][o] += h2p[r][o]  (LDS f32 atomics, no global atomics).
// Partial accumulator written coalesced to part[blockIdx][TILE*16].
// ---------------------------------------------------------------------------
__global__ __launch_bounds__(512) void scan_kernel(const int* __restrict__ ei,
                                                   const float* __restrict__ h2p,
                                                   float* __restrict__ part, int E) {
    __shared__ float acc[TILE * OUT_C];      // 64 KB
    const int t = blockIdx.x / KCH;
    const int k = blockIdx.x - t * KCH;
    for (int i = threadIdx.x; i < TILE * OUT_C; i += 512) acc[i] = 0.f;
    __syncthreads();

    const int chunk = (((E + KCH - 1) / KCH) + 3) & ~3;
    const int beg = k * chunk;
    const int end = min(E, beg + chunk);
    const int* cols = ei + E;

    const int nv = (end > beg) ? (end - beg) >> 2 : 0;
    const i32x4* cv = (const i32x4*)(cols + beg);
    for (int i = threadIdx.x; i < nv; i += 512) {
        i32x4 c = cv[i];
        const int ebase = beg + (i << 2);
#pragma unroll
        for (int j = 0; j < 4; ++j) {
            int cj = c[j];
            if ((cj >> 10) == t) {
                int r = ei[ebase + j];
                int cl = cj & (TILE - 1);
                const f32x4* hv = (const f32x4*)(h2p + (size_t)r * OUT_C);
#pragma unroll
                for (int q = 0; q < 4; ++q) {
                    f32x4 h = hv[q];
                    atomicAdd(&acc[cl * OUT_C + 4 * q + 0], h.x);
                    atomicAdd(&acc[cl * OUT_C + 4 * q + 1], h.y);
                    atomicAdd(&acc[cl * OUT_C + 4 * q + 2], h.z);
                    atomicAdd(&acc[cl * OUT_C + 4 * q + 3], h.w);
                }
            }
        }
    }
    for (int e = beg + (nv << 2) + threadIdx.x; e < end; e += 512) {
        int cj = cols[e];
        if ((cj >> 10) == t) {
            int r = ei[e];
            int cl = cj & (TILE - 1);
            const f32x4* hv = (const f32x4*)(h2p + (size_t)r * OUT_C);
#pragma unroll
            for (int q = 0; q < 4; ++q) {
                f32x4 h = hv[q];
                atomicAdd(&acc[cl * OUT_C + 4 * q + 0], h.x);
                atomicAdd(&acc[cl * OUT_C + 4 * q + 1], h.y);
                atomicAdd(&acc[cl * OUT_C + 4 * q + 2], h.z);
                atomicAdd(&acc[cl * OUT_C + 4 * q + 3], h.w);
            }
        }
    }
    __syncthreads();
    float* pout = part + (size_t)blockIdx.x * (TILE * OUT_C);
    for (int i = threadIdx.x; i < TILE * OUT_C; i += 512)
        pout[i] = acc[i];
}

// ---------------------------------------------------------------------------
// K6: out[n][o] = cconst[o] + dsq[n] * sum_k part[(t*KCH+k)][ (n&1023)*16+o ]
// ---------------------------------------------------------------------------
__global__ void reduce_kernel(const float* __restrict__ part, const float* __restrict__ dsq,
                              const float* __restrict__ cconst, float* __restrict__ out,
                              int N) {
    int id = blockIdx.x * 256 + threadIdx.x;
    if (id >= N * OUT_C) return;
    int n = id >> 4, o = id & 15;
    int t = n >> 10, i = n & (TILE - 1);
    const float* p = part + (size_t)(t * KCH) * (TILE * OUT_C) + i * OUT_C + o;
    float s = p[0];
    s += p[1 * TILE * OUT_C];
    s += p[2 * TILE * OUT_C];
    s += p[3 * TILE * OUT_C];
    out[id] = fmaf(dsq[n], s, cconst[o]);
}

// ---------------------------------------------------------------------------
extern "C" void kernel_launch(void* const* d_in, const int* in_sizes, int n_in,
                              void* d_out, int out_size, void* d_ws, size_t ws_size,
                              hipStream_t stream) {
    const float* x  = (const float*)d_in[0];
    const int*   ei = (const int*)d_in[1];
    const float* W1 = (const float*)d_in[2];
    const float* b1 = (const float*)d_in[3];
    const float* W2 = (const float*)d_in[4];
    const float* b2 = (const float*)d_in[5];
    float* out = (float*)d_out;

    const int N = in_sizes[0] / IN_C;
    const int E = in_sizes[1] / 2;
    const int NB = (N + 255) / 256;
    const int NT = (N + TILE - 1) / TILE;       // 49

    // workspace (4-byte units):
    // Wc[8192] | cconst[16] | dsq[N] | h2p[16N] | deg[N] | part[NT*KCH*TILE*16]
    float* ws     = (float*)d_ws;
    float* Wc     = ws;
    float* cconst = ws + 16 * IN_C;
    float* dsq    = cconst + 16;
    float* h2p    = dsq + N;
    int*   deg    = (int*)(h2p + (size_t)16 * N);
    float* part   = (float*)(deg + N);
    // total ~ 17 MB (<< ws poison size 400 MB)

    hipLaunchKernelGGL(prep_kernel, dim3(33 + NB), dim3(256), 0, stream,
                       W1, b1, W2, b2, Wc, cconst, deg, N);
    hipLaunchKernelGGL(hist_kernel, dim3(NT * KCH), dim3(512), 0, stream, ei, deg, E, N);
    hipLaunchKernelGGL(dsq_kernel, dim3(NB), dim3(256), 0, stream, deg, dsq, N);
    hipLaunchKernelGGL(h2_kernel, dim3(512), dim3(256), 0, stream, x, Wc, dsq, h2p, N);
    hipLaunchKernelGGL(scan_kernel, dim3(NT * KCH), dim3(512), 0, stream, ei, h2p, part, E);
    hipLaunchKernelGGL(reduce_kernel, dim3((N * OUT_C + 255) / 256), dim3(256), 0, stream,
                       part, dsq, cconst, out, N);
}

// Round 6
// 222.141 us; speedup vs baseline: 1.2480x; 1.2480x over previous
//
#include <hip/hip_runtime.h>
#include <hip/hip_bf16.h>

#define IN_C 512
#define HID_C 128
#define OUT_C 16
#define TILE 512       // destination nodes per tile
#define TSH  9         // log2(TILE)
#define KCH  5         // edge chunks per tile (scan)
#define KCH_H 32       // edge chunks per tile (hist)
#define QCAP 8160      // LDS queue entries (keeps total LDS < 64 KB)

typedef float f32x4 __attribute__((ext_vector_type(4)));
typedef int   i32x4 __attribute__((ext_vector_type(4)));

// ---------------------------------------------------------------------------
// K1: folded weights + bias const.
//   Wc[o][k] = sum_h W2[o][h] * W1[h][k]   (16 x 512)
//   cconst[o] = b2[o] + sum_h b1[h] * W2[o][h]
// ---------------------------------------------------------------------------
__global__ void prep_kernel(const float* __restrict__ W1, const float* __restrict__ b1,
                            const float* __restrict__ W2, const float* __restrict__ b2,
                            float* __restrict__ Wc, float* __restrict__ cconst) {
    if (blockIdx.x < 32) {
        int idx = blockIdx.x * 256 + threadIdx.x;   // 0 .. 8191
        int o = idx >> 9;
        int k = idx & 511;
        float s = 0.f;
#pragma unroll 8
        for (int h = 0; h < HID_C; ++h)
            s = fmaf(W2[o * HID_C + h], W1[h * IN_C + k], s);
        Wc[o * IN_C + k] = s;
    } else {
        if (threadIdx.x < OUT_C) {
            int o = threadIdx.x;
            float s = b2[o];
            for (int h = 0; h < HID_C; ++h)
                s = fmaf(b1[h], W2[o * HID_C + h], s);
            cconst[o] = s;
        }
    }
}

// ---------------------------------------------------------------------------
// K2: per-(tile,chunk) degree histogram. Block (t,k) reads chunk k's cols,
// counts those in tile t into a 2KB LDS hist, writes partials coalesced.
// No global atomics.
// ---------------------------------------------------------------------------
__global__ __launch_bounds__(256) void hist_kernel(const int* __restrict__ ei,
                                                   int* __restrict__ phist, int E) {
    __shared__ int h[TILE];
    const int t = blockIdx.x / KCH_H;
    const int k = blockIdx.x - t * KCH_H;
    for (int i = threadIdx.x; i < TILE; i += 256) h[i] = 0;
    __syncthreads();

    const int chunk = (((E + KCH_H - 1) / KCH_H) + 3) & ~3;
    const int beg = k * chunk;
    const int end = min(E, beg + chunk);
    const int* cols = ei + E;

    const int nv = (end > beg) ? ((end - beg) >> 2) : 0;
    const i32x4* cv = (const i32x4*)(cols + beg);
    for (int i = threadIdx.x; i < nv; i += 256) {
        i32x4 c = cv[i];
#pragma unroll
        for (int j = 0; j < 4; ++j) {
            int cj = c[j];
            if ((cj >> TSH) == t) atomicAdd(&h[cj & (TILE - 1)], 1);
        }
    }
    for (int e = beg + (nv << 2) + threadIdx.x; e < end; e += 256) {
        int cj = cols[e];
        if ((cj >> TSH) == t) atomicAdd(&h[cj & (TILE - 1)], 1);
    }
    __syncthreads();
    int* out = phist + (size_t)blockIdx.x * TILE;   // layout [t][k][i]
    for (int i = threadIdx.x; i < TILE; i += 256) out[i] = h[i];
}

// K3: dsq[n] = sqrt(sum_k phist[t][k][i])
__global__ void dsqk_kernel(const int* __restrict__ phist, float* __restrict__ dsq, int N) {
    int n = blockIdx.x * 256 + threadIdx.x;
    if (n >= N) return;
    int t = n >> TSH, i = n & (TILE - 1);
    const int* p = phist + (size_t)t * KCH_H * TILE + i;
    int s = 0;
#pragma unroll
    for (int k = 0; k < KCH_H; ++k) s += p[k * TILE];
    dsq[n] = sqrtf((float)s);
}

// ---------------------------------------------------------------------------
// K4: h2p[r][o] = dsq[r] * (x[r] @ Wc^T)[o].
// Wc in LDS (32KB); each wave processes 4 rows/iter so the 32 ds_read_b128
// per group are amortized 4x. Freeing 128 weight-VGPRs lifts occupancy.
// ---------------------------------------------------------------------------
__global__ __launch_bounds__(256) void h2_kernel(const float* __restrict__ x,
                                                 const float* __restrict__ WcG,
                                                 const float* __restrict__ dsq,
                                                 float* __restrict__ h2p, int N) {
    __shared__ float wl[16 * IN_C];
    for (int i = threadIdx.x; i < (16 * IN_C) / 4; i += 256)
        ((f32x4*)wl)[i] = ((const f32x4*)WcG)[i];
    __syncthreads();

    const int lane = threadIdx.x & 63;
    const int wid = (blockIdx.x * 256 + threadIdx.x) >> 6;
    const int nw  = (gridDim.x * 256) >> 6;

    for (int r0 = wid * 4; r0 < N; r0 += nw * 4) {
        const int rmax = min(4, N - r0);
        f32x4 a0[4], a1[4];
#pragma unroll
        for (int rr = 0; rr < 4; ++rr) {
            int r = r0 + (rr < rmax ? rr : 0);
            a0[rr] = *(const f32x4*)(x + (size_t)r * IN_C + 4 * lane);
            a1[rr] = *(const f32x4*)(x + (size_t)r * IN_C + 256 + 4 * lane);
        }
        float p[4][16];
#pragma unroll
        for (int oo = 0; oo < 16; ++oo) {
            f32x4 w0 = *(const f32x4*)(wl + oo * IN_C + 4 * lane);
            f32x4 w1 = *(const f32x4*)(wl + oo * IN_C + 256 + 4 * lane);
#pragma unroll
            for (int rr = 0; rr < 4; ++rr) {
                float s = a0[rr].x * w0.x;
                s = fmaf(a0[rr].y, w0.y, s);
                s = fmaf(a0[rr].z, w0.z, s);
                s = fmaf(a0[rr].w, w0.w, s);
                s = fmaf(a1[rr].x, w1.x, s);
                s = fmaf(a1[rr].y, w1.y, s);
                s = fmaf(a1[rr].z, w1.z, s);
                s = fmaf(a1[rr].w, w1.w, s);
                p[rr][oo] = s;
            }
        }
        float v[4];
#pragma unroll
        for (int rr = 0; rr < 4; ++rr) {
#define RSTEP(MASK, HALF)                                              \
            {                                                          \
                const bool hi = (lane & MASK) != 0;                    \
                _Pragma("unroll")                                      \
                for (int ii = 0; ii < HALF; ++ii) {                    \
                    float send = hi ? p[rr][ii] : p[rr][ii + HALF];    \
                    float recv = __shfl_xor(send, MASK, 64);           \
                    float keep = hi ? p[rr][ii + HALF] : p[rr][ii];    \
                    p[rr][ii] = keep + recv;                           \
                }                                                      \
            }
            RSTEP(1, 8)
            RSTEP(2, 4)
            RSTEP(4, 2)
            RSTEP(8, 1)
#undef RSTEP
            v[rr] = p[rr][0];
        }
        // merge 4 rows across quarters: quarter q ends up holding row q
        const bool h16 = (lane & 16) != 0;
        float sA = h16 ? v[0] : v[1];
        float mA = (h16 ? v[1] : v[0]) + __shfl_xor(sA, 16, 64);
        float sB = h16 ? v[2] : v[3];
        float mB = (h16 ? v[3] : v[2]) + __shfl_xor(sB, 16, 64);
        const bool h32 = (lane & 32) != 0;
        float sC = h32 ? mA : mB;
        float f  = (h32 ? mB : mA) + __shfl_xor(sC, 32, 64);
        const int qq = lane >> 4, jj = lane & 15;
        const int oo = ((jj & 1) << 3) | ((jj & 2) << 1) | ((jj & 4) >> 1) | ((jj & 8) >> 3);
        if (qq < rmax) {
            int r = r0 + qq;
            h2p[(size_t)r * OUT_C + oo] = f * dsq[r];
        }
    }
}

// ---------------------------------------------------------------------------
// K5: tile-scan, compact-then-process.
// Scan phase: prefetched col reads, push matching (cl,r) into LDS queue.
// Process phase (drain): 16 lanes/edge — one 64B h2p line + 1 LDS f32 atomic
// per lane, independent iterations. No global atomics, no random global writes.
// ---------------------------------------------------------------------------
__global__ __launch_bounds__(512) void scan_kernel(const int* __restrict__ ei,
                                                   const float* __restrict__ h2p,
                                                   float* __restrict__ part, int E) {
    __shared__ float acc[TILE * OUT_C];   // 32 KB
    __shared__ int   q[QCAP];             // ~32 KB
    __shared__ int   qn;
    const int t = blockIdx.x / KCH;
    const int k = blockIdx.x - t * KCH;
    for (int i = threadIdx.x; i < TILE * OUT_C; i += 512) acc[i] = 0.f;
    if (threadIdx.x == 0) qn = 0;
    __syncthreads();

    const int chunk = (((E + KCH - 1) / KCH) + 3) & ~3;
    const int beg = k * chunk;
    const int end = min(E, beg + chunk);
    const int* cols = ei + E;
    const int nv = (end > beg) ? ((end - beg) >> 2) : 0;
    const i32x4* cv = (const i32x4*)(cols + beg);
    const int iters = (nv + 511) >> 9;

    const int g = threadIdx.x >> 4;   // 32 groups of 16 lanes
    const int o = threadIdx.x & 15;

    i32x4 c;
    int  i0 = threadIdx.x;
    bool have = (i0 < nv);
    if (have) c = cv[i0];
    for (int it = 0; it < iters; ++it) {
        int  i1 = i0 + 512;
        i32x4 cnx;
        bool havenx = (i1 < nv);
        if (havenx) cnx = cv[i1];          // prefetch across the barrier
        if (have) {
            int e0 = beg + (i0 << 2);
#pragma unroll
            for (int j = 0; j < 4; ++j) {
                int cj = c[j];
                if ((cj >> TSH) == t) {
                    int r = ei[e0 + j];
                    int pos = atomicAdd(&qn, 1);
                    if (pos < QCAP) q[pos] = ((cj & (TILE - 1)) << 16) | r;
                }
            }
        }
        __syncthreads();
        if (qn > QCAP - 2048) {           // uniform; never drops (<=2048 pushes/iter)
            int tot = min(qn, QCAP);
            for (int idx = g; idx < tot; idx += 32) {
                int pk = q[idx];
                float h = h2p[(size_t)(pk & 0xffff) * OUT_C + o];
                atomicAdd(&acc[((pk >> 16) << 4) + o], h);
            }
            __syncthreads();
            if (threadIdx.x == 0) qn = 0;
        }
        __syncthreads();
        c = cnx; have = havenx; i0 = i1;
    }
    // scalar tail (chunk is 4-aligned so normally empty)
    for (int e = beg + (nv << 2) + threadIdx.x; e < end; e += 512) {
        int cj = cols[e];
        if ((cj >> TSH) == t) {
            int r = ei[e];
            int pos = atomicAdd(&qn, 1);
            if (pos < QCAP) q[pos] = ((cj & (TILE - 1)) << 16) | r;
        }
    }
    __syncthreads();
    {
        int tot = min(qn, QCAP);
        for (int idx = g; idx < tot; idx += 32) {
            int pk = q[idx];
            float h = h2p[(size_t)(pk & 0xffff) * OUT_C + o];
            atomicAdd(&acc[((pk >> 16) << 4) + o], h);
        }
    }
    __syncthreads();
    float* po = part + (size_t)blockIdx.x * (TILE * OUT_C);
    for (int i = threadIdx.x; i < TILE * OUT_C; i += 512) po[i] = acc[i];
}

// ---------------------------------------------------------------------------
// K6: out[n][o] = cconst[o] + dsq[n] * sum_k part[t][k][i][o]
// ---------------------------------------------------------------------------
__global__ void reduce_kernel(const float* __restrict__ part, const float* __restrict__ dsq,
                              const float* __restrict__ cconst, float* __restrict__ out,
                              int N) {
    int id = blockIdx.x * 256 + threadIdx.x;
    if (id >= N * OUT_C) return;
    int n = id >> 4, o = id & 15;
    int t = n >> TSH, i = n & (TILE - 1);
    const float* p = part + (size_t)t * KCH * (TILE * OUT_C) + i * OUT_C + o;
    float s = 0.f;
#pragma unroll
    for (int k = 0; k < KCH; ++k) s += p[(size_t)k * (TILE * OUT_C)];
    out[id] = fmaf(dsq[n], s, cconst[o]);
}

// ---------------------------------------------------------------------------
extern "C" void kernel_launch(void* const* d_in, const int* in_sizes, int n_in,
                              void* d_out, int out_size, void* d_ws, size_t ws_size,
                              hipStream_t stream) {
    const float* x  = (const float*)d_in[0];
    const int*   ei = (const int*)d_in[1];
    const float* W1 = (const float*)d_in[2];
    const float* b1 = (const float*)d_in[3];
    const float* W2 = (const float*)d_in[4];
    const float* b2 = (const float*)d_in[5];
    float* out = (float*)d_out;

    const int N = in_sizes[0] / IN_C;
    const int E = in_sizes[1] / 2;
    const int NT = (N + TILE - 1) / TILE;      // 98

    // workspace (4-byte units):
    // Wc[8192] | cconst[16] | dsq[N] | h2p[16N] | phist[NT*KCH_H*TILE] | part[NT*KCH*TILE*16]
    float* ws     = (float*)d_ws;
    float* Wc     = ws;
    float* cconst = ws + 16 * IN_C;
    float* dsq    = cconst + 16;
    float* h2p    = dsq + N;
    int*   phist  = (int*)(h2p + (size_t)16 * N);
    float* part   = (float*)(phist + (size_t)NT * KCH_H * TILE);
    // total ~ 26 MB

    hipLaunchKernelGGL(prep_kernel, dim3(33), dim3(256), 0, stream,
                       W1, b1, W2, b2, Wc, cconst);
    hipLaunchKernelGGL(hist_kernel, dim3(NT * KCH_H), dim3(256), 0, stream, ei, phist, E);
    hipLaunchKernelGGL(dsqk_kernel, dim3((N + 255) / 256), dim3(256), 0, stream, phist, dsq, N);
    hipLaunchKernelGGL(h2_kernel, dim3(768), dim3(256), 0, stream, x, Wc, dsq, h2p, N);
    hipLaunchKernelGGL(scan_kernel, dim3(NT * KCH), dim3(512), 0, stream, ei, h2p, part, E);
    hipLaunchKernelGGL(reduce_kernel, dim3((N * OUT_C + 255) / 256), dim3(256), 0, stream,
                       part, dsq, cconst, out, N);
}

// Round 7
// 189.278 us; speedup vs baseline: 1.4646x; 1.1736x over previous
//
#include <hip/hip_runtime.h>
#include <hip/hip_bf16.h>

#define IN_C 512
#define HID_C 128
#define OUT_C 16
#define TILE 512       // destination nodes per scan tile
#define TSH  9         // log2(TILE)
#define KCH  5         // edge chunks per tile (scan)
#define STILE 4096     // nodes per hist supertile
#define SSH  12        // log2(STILE)
#define KCH_H 24       // edge chunks per supertile (hist)
#define QCAP 8160      // LDS queue entries (acc 32KB + q ~32KB < 64KB)

typedef float f32x4 __attribute__((ext_vector_type(4)));
typedef int   i32x4 __attribute__((ext_vector_type(4)));

// ---------------------------------------------------------------------------
// K1: folded weights + bias const.
//   Wc[o][k] = sum_h W2[o][h] * W1[h][k]   (16 x 512)
//   cconst[o] = b2[o] + sum_h b1[h] * W2[o][h]
// ---------------------------------------------------------------------------
__global__ void prep_kernel(const float* __restrict__ W1, const float* __restrict__ b1,
                            const float* __restrict__ W2, const float* __restrict__ b2,
                            float* __restrict__ Wc, float* __restrict__ cconst) {
    if (blockIdx.x < 32) {
        int idx = blockIdx.x * 256 + threadIdx.x;   // 0 .. 8191
        int o = idx >> 9;
        int k = idx & 511;
        float s = 0.f;
#pragma unroll 8
        for (int h = 0; h < HID_C; ++h)
            s = fmaf(W2[o * HID_C + h], W1[h * IN_C + k], s);
        Wc[o * IN_C + k] = s;
    } else {
        if (threadIdx.x < OUT_C) {
            int o = threadIdx.x;
            float s = b2[o];
            for (int h = 0; h < HID_C; ++h)
                s = fmaf(b1[h], W2[o * HID_C + h], s);
            cconst[o] = s;
        }
    }
}

// ---------------------------------------------------------------------------
// K2: supertile degree histogram. Block (st,k) streams chunk k's cols once,
// counts those in supertile st (4096 nodes, 16KB LDS), writes partials
// coalesced. Col-read volume: 13x edge list (vs 98x before).
// ---------------------------------------------------------------------------
__global__ __launch_bounds__(256) void hist_kernel(const int* __restrict__ ei,
                                                   int* __restrict__ phist, int E) {
    __shared__ int h[STILE];
    const int st = blockIdx.x / KCH_H;
    const int k = blockIdx.x - st * KCH_H;
    for (int i = threadIdx.x; i < STILE; i += 256) h[i] = 0;
    __syncthreads();

    const int chunk = (((E + KCH_H - 1) / KCH_H) + 3) & ~3;
    const int beg = k * chunk;
    const int end = min(E, beg + chunk);
    const int* cols = ei + E;

    const int nv = (end > beg) ? ((end - beg) >> 2) : 0;
    const i32x4* cv = (const i32x4*)(cols + beg);
    for (int i = threadIdx.x; i < nv; i += 256) {
        i32x4 c = cv[i];
#pragma unroll
        for (int j = 0; j < 4; ++j) {
            int cj = c[j];
            if ((cj >> SSH) == st) atomicAdd(&h[cj & (STILE - 1)], 1);
        }
    }
    for (int e = beg + (nv << 2) + threadIdx.x; e < end; e += 256) {
        int cj = cols[e];
        if ((cj >> SSH) == st) atomicAdd(&h[cj & (STILE - 1)], 1);
    }
    __syncthreads();
    int* outp = phist + (size_t)blockIdx.x * STILE;   // layout [st][k][i]
    for (int i = threadIdx.x; i < STILE; i += 256) outp[i] = h[i];
}

// K3: dsq[n] = sqrt(sum_k phist[st][k][i])
__global__ void dsqk_kernel(const int* __restrict__ phist, float* __restrict__ dsq, int N) {
    int n = blockIdx.x * 256 + threadIdx.x;
    if (n >= N) return;
    int st = n >> SSH, i = n & (STILE - 1);
    const int* p = phist + (size_t)st * KCH_H * STILE + i;
    int s = 0;
#pragma unroll
    for (int k = 0; k < KCH_H; ++k) s += p[k * STILE];
    dsq[n] = sqrtf((float)s);
}

// ---------------------------------------------------------------------------
// K4: h2p[r][o] = dsq[r] * (x[r] @ Wc^T)[o].
// Wc in LDS (32KB); each wave processes 4 rows/iter.
// ---------------------------------------------------------------------------
__global__ __launch_bounds__(256) void h2_kernel(const float* __restrict__ x,
                                                 const float* __restrict__ WcG,
                                                 const float* __restrict__ dsq,
                                                 float* __restrict__ h2p, int N) {
    __shared__ float wl[16 * IN_C];
    for (int i = threadIdx.x; i < (16 * IN_C) / 4; i += 256)
        ((f32x4*)wl)[i] = ((const f32x4*)WcG)[i];
    __syncthreads();

    const int lane = threadIdx.x & 63;
    const int wid = (blockIdx.x * 256 + threadIdx.x) >> 6;
    const int nw  = (gridDim.x * 256) >> 6;

    for (int r0 = wid * 4; r0 < N; r0 += nw * 4) {
        const int rmax = min(4, N - r0);
        f32x4 a0[4], a1[4];
#pragma unroll
        for (int rr = 0; rr < 4; ++rr) {
            int r = r0 + (rr < rmax ? rr : 0);
            a0[rr] = *(const f32x4*)(x + (size_t)r * IN_C + 4 * lane);
            a1[rr] = *(const f32x4*)(x + (size_t)r * IN_C + 256 + 4 * lane);
        }
        float p[4][16];
#pragma unroll
        for (int oo = 0; oo < 16; ++oo) {
            f32x4 w0 = *(const f32x4*)(wl + oo * IN_C + 4 * lane);
            f32x4 w1 = *(const f32x4*)(wl + oo * IN_C + 256 + 4 * lane);
#pragma unroll
            for (int rr = 0; rr < 4; ++rr) {
                float s = a0[rr].x * w0.x;
                s = fmaf(a0[rr].y, w0.y, s);
                s = fmaf(a0[rr].z, w0.z, s);
                s = fmaf(a0[rr].w, w0.w, s);
                s = fmaf(a1[rr].x, w1.x, s);
                s = fmaf(a1[rr].y, w1.y, s);
                s = fmaf(a1[rr].z, w1.z, s);
                s = fmaf(a1[rr].w, w1.w, s);
                p[rr][oo] = s;
            }
        }
        float v[4];
#pragma unroll
        for (int rr = 0; rr < 4; ++rr) {
#define RSTEP(MASK, HALF)                                              \
            {                                                          \
                const bool hi = (lane & MASK) != 0;                    \
                _Pragma("unroll")                                      \
                for (int ii = 0; ii < HALF; ++ii) {                    \
                    float send = hi ? p[rr][ii] : p[rr][ii + HALF];    \
                    float recv = __shfl_xor(send, MASK, 64);           \
                    float keep = hi ? p[rr][ii + HALF] : p[rr][ii];    \
                    p[rr][ii] = keep + recv;                           \
                }                                                      \
            }
            RSTEP(1, 8)
            RSTEP(2, 4)
            RSTEP(4, 2)
            RSTEP(8, 1)
#undef RSTEP
            v[rr] = p[rr][0];
        }
        const bool h16 = (lane & 16) != 0;
        float sA = h16 ? v[0] : v[1];
        float mA = (h16 ? v[1] : v[0]) + __shfl_xor(sA, 16, 64);
        float sB = h16 ? v[2] : v[3];
        float mB = (h16 ? v[3] : v[2]) + __shfl_xor(sB, 16, 64);
        const bool h32 = (lane & 32) != 0;
        float sC = h32 ? mA : mB;
        float f  = (h32 ? mB : mA) + __shfl_xor(sC, 32, 64);
        const int qq = lane >> 4, jj = lane & 15;
        const int oo = ((jj & 1) << 3) | ((jj & 2) << 1) | ((jj & 4) >> 1) | ((jj & 8) >> 3);
        if (qq < rmax) {
            int r = r0 + qq;
            h2p[(size_t)r * OUT_C + oo] = f * dsq[r];
        }
    }
}

// ---------------------------------------------------------------------------
// K5: barrier-free tile-scan. Phase A: stream chunk cols (4-way batched i32x4,
// 16 loads in flight/wave), push packed (cl<<16)|row into LDS queue (row < 2^16
// since N=50000). Phase B (after ONE barrier): drain, 16 lanes/edge, one 64B
// h2p line + 1 LDS f32 atomic per lane. Overflow fallback inlines the edge
// (statistically unreachable: E[pushes]=1633, QCAP=8160).
// ---------------------------------------------------------------------------
__global__ __launch_bounds__(512) void scan_kernel(const int* __restrict__ ei,
                                                   const float* __restrict__ h2p,
                                                   float* __restrict__ part, int E) {
    __shared__ float acc[TILE * OUT_C];   // 32 KB
    __shared__ int   q[QCAP];             // ~32 KB
    __shared__ int   qn;
    const int t = blockIdx.x / KCH;
    const int k = blockIdx.x - t * KCH;
    for (int i = threadIdx.x; i < TILE * OUT_C; i += 512) acc[i] = 0.f;
    if (threadIdx.x == 0) qn = 0;
    __syncthreads();

    const int chunk = (((E + KCH - 1) / KCH) + 3) & ~3;
    const int beg = k * chunk;
    const int end = min(E, beg + chunk);
    const int* cols = ei + E;
    const int nv = (end > beg) ? ((end - beg) >> 2) : 0;
    const i32x4* cv = (const i32x4*)(cols + beg);

#define PROC(cvec, ib)                                                        \
    {                                                                         \
        const int e0 = beg + ((ib) << 2);                                     \
        _Pragma("unroll")                                                     \
        for (int j = 0; j < 4; ++j) {                                         \
            int cj = cvec[j];                                                 \
            if ((cj >> TSH) == t) {                                           \
                int r = ei[e0 + j];                                           \
                int pos = atomicAdd(&qn, 1);                                  \
                if (pos < QCAP) {                                             \
                    q[pos] = ((cj & (TILE - 1)) << 16) | r;                   \
                } else {                                                      \
                    int cl = cj & (TILE - 1);                                 \
                    for (int oo = 0; oo < OUT_C; ++oo)                        \
                        atomicAdd(&acc[(cl << 4) + oo],                       \
                                  h2p[(size_t)r * OUT_C + oo]);               \
                }                                                             \
            }                                                                 \
        }                                                                     \
    }

    int i = threadIdx.x;
    for (; i + 3 * 512 < nv; i += 4 * 512) {
        i32x4 v0 = cv[i];
        i32x4 v1 = cv[i + 512];
        i32x4 v2 = cv[i + 1024];
        i32x4 v3 = cv[i + 1536];
        PROC(v0, i)
        PROC(v1, i + 512)
        PROC(v2, i + 1024)
        PROC(v3, i + 1536)
    }
    for (; i < nv; i += 512) {
        i32x4 v = cv[i];
        PROC(v, i)
    }
    for (int e = beg + (nv << 2) + threadIdx.x; e < end; e += 512) {
        int cj = cols[e];
        if ((cj >> TSH) == t) {
            int r = ei[e];
            int pos = atomicAdd(&qn, 1);
            if (pos < QCAP) q[pos] = ((cj & (TILE - 1)) << 16) | r;
            else {
                int cl = cj & (TILE - 1);
                for (int oo = 0; oo < OUT_C; ++oo)
                    atomicAdd(&acc[(cl << 4) + oo], h2p[(size_t)r * OUT_C + oo]);
            }
        }
    }
#undef PROC
    __syncthreads();

    const int tot = min(qn, QCAP);
    const int g = threadIdx.x >> 4;   // 32 groups of 16 lanes
    const int o = threadIdx.x & 15;
#pragma unroll 2
    for (int idx = g; idx < tot; idx += 32) {
        int pk = q[idx];
        float h = h2p[(size_t)(pk & 0xffff) * OUT_C + o];
        atomicAdd(&acc[((pk >> 16) << 4) + o], h);
    }
    __syncthreads();
    float* po = part + (size_t)blockIdx.x * (TILE * OUT_C);
    for (int i2 = threadIdx.x; i2 < TILE * OUT_C; i2 += 512) po[i2] = acc[i2];
}

// ---------------------------------------------------------------------------
// K6: out[n][o] = cconst[o] + dsq[n] * sum_k part[t][k][i][o]
// ---------------------------------------------------------------------------
__global__ void reduce_kernel(const float* __restrict__ part, const float* __restrict__ dsq,
                              const float* __restrict__ cconst, float* __restrict__ out,
                              int N) {
    int id = blockIdx.x * 256 + threadIdx.x;
    if (id >= N * OUT_C) return;
    int n = id >> 4, o = id & 15;
    int t = n >> TSH, i = n & (TILE - 1);
    const float* p = part + (size_t)t * KCH * (TILE * OUT_C) + i * OUT_C + o;
    float s = 0.f;
#pragma unroll
    for (int k = 0; k < KCH; ++k) s += p[(size_t)k * (TILE * OUT_C)];
    out[id] = fmaf(dsq[n], s, cconst[o]);
}

// ---------------------------------------------------------------------------
extern "C" void kernel_launch(void* const* d_in, const int* in_sizes, int n_in,
                              void* d_out, int out_size, void* d_ws, size_t ws_size,
                              hipStream_t stream) {
    const float* x  = (const float*)d_in[0];
    const int*   ei = (const int*)d_in[1];
    const float* W1 = (const float*)d_in[2];
    const float* b1 = (const float*)d_in[3];
    const float* W2 = (const float*)d_in[4];
    const float* b2 = (const float*)d_in[5];
    float* out = (float*)d_out;

    const int N = in_sizes[0] / IN_C;    // 50000 (row index must fit 16 bits)
    const int E = in_sizes[1] / 2;
    const int NT = (N + TILE - 1) / TILE;        // 98
    const int ST = (N + STILE - 1) / STILE;      // 13

    // workspace (4-byte units):
    // Wc[8192] | cconst[16] | dsq[N] | h2p[16N] | phist[ST*KCH_H*STILE] | part[NT*KCH*TILE*16]
    float* ws     = (float*)d_ws;
    float* Wc     = ws;
    float* cconst = ws + 16 * IN_C;
    float* dsq    = cconst + 16;
    float* h2p    = dsq + N;
    int*   phist  = (int*)(h2p + (size_t)16 * N);
    float* part   = (float*)(phist + (size_t)ST * KCH_H * STILE);
    // total ~ 25 MB

    hipLaunchKernelGGL(prep_kernel, dim3(33), dim3(256), 0, stream,
                       W1, b1, W2, b2, Wc, cconst);
    hipLaunchKernelGGL(hist_kernel, dim3(ST * KCH_H), dim3(256), 0, stream, ei, phist, E);
    hipLaunchKernelGGL(dsqk_kernel, dim3((N + 255) / 256), dim3(256), 0, stream, phist, dsq, N);
    hipLaunchKernelGGL(h2_kernel, dim3(768), dim3(256), 0, stream, x, Wc, dsq, h2p, N);
    hipLaunchKernelGGL(scan_kernel, dim3(NT * KCH), dim3(512), 0, stream, ei, h2p, part, E);
    hipLaunchKernelGGL(reduce_kernel, dim3((N * OUT_C + 255) / 256), dim3(256), 0, stream,
                       part, dsq, cconst, out, N);
}

// Round 9
// 104.912 us; speedup vs baseline: 2.6424x; 1.8042x over previous
//
#include <hip/hip_runtime.h>
#include <hip/hip_bf16.h>

#define IN_C 512
#define HID_C 128
#define OUT_C 16
#define STILE 4096     // nodes per hist supertile
#define SSH  12        // log2(STILE)
#define KCH_H 24       // edge chunks per supertile (hist)

typedef float f32x4 __attribute__((ext_vector_type(4)));
typedef int   i32x4 __attribute__((ext_vector_type(4)));

// ---------------------------------------------------------------------------
// K1: folded weights + bias const.
//   Wc[o][k] = sum_h W2[o][h] * W1[h][k]   (16 x 512)
//   cconst[o] = b2[o] + sum_h b1[h] * W2[o][h]
// ---------------------------------------------------------------------------
__global__ void prep_kernel(const float* __restrict__ W1, const float* __restrict__ b1,
                            const float* __restrict__ W2, const float* __restrict__ b2,
                            float* __restrict__ Wc, float* __restrict__ cconst) {
    if (blockIdx.x < 32) {
        int idx = blockIdx.x * 256 + threadIdx.x;   // 0 .. 8191
        int o = idx >> 9;
        int k = idx & 511;
        float s = 0.f;
#pragma unroll 8
        for (int h = 0; h < HID_C; ++h)
            s = fmaf(W2[o * HID_C + h], W1[h * IN_C + k], s);
        Wc[o * IN_C + k] = s;
    } else {
        if (threadIdx.x < OUT_C) {
            int o = threadIdx.x;
            float s = b2[o];
            for (int h = 0; h < HID_C; ++h)
                s = fmaf(b1[h], W2[o * HID_C + h], s);
            cconst[o] = s;
        }
    }
}

// ---------------------------------------------------------------------------
// K2: supertile degree histogram (no global atomics).
// Block (st,k) streams chunk k's cols, counts those in supertile st into
// 16KB LDS, writes partials coalesced.
// ---------------------------------------------------------------------------
__global__ __launch_bounds__(256) void hist_kernel(const int* __restrict__ ei,
                                                   int* __restrict__ phist, int E) {
    __shared__ int h[STILE];
    const int st = blockIdx.x / KCH_H;
    const int k = blockIdx.x - st * KCH_H;
    for (int i = threadIdx.x; i < STILE; i += 256) h[i] = 0;
    __syncthreads();

    const int chunk = (((E + KCH_H - 1) / KCH_H) + 3) & ~3;
    const int beg = k * chunk;
    const int end = min(E, beg + chunk);
    const int* cols = ei + E;

    const int nv = (end > beg) ? ((end - beg) >> 2) : 0;
    const i32x4* cv = (const i32x4*)(cols + beg);
    for (int i = threadIdx.x; i < nv; i += 256) {
        i32x4 c = cv[i];
#pragma unroll
        for (int j = 0; j < 4; ++j) {
            int cj = c[j];
            if ((cj >> SSH) == st) atomicAdd(&h[cj & (STILE - 1)], 1);
        }
    }
    for (int e = beg + (nv << 2) + threadIdx.x; e < end; e += 256) {
        int cj = cols[e];
        if ((cj >> SSH) == st) atomicAdd(&h[cj & (STILE - 1)], 1);
    }
    __syncthreads();
    int* outp = phist + (size_t)blockIdx.x * STILE;   // layout [st][k][i]
    for (int i = threadIdx.x; i < STILE; i += 256) outp[i] = h[i];
}

// K3: dsq[n] = sqrt(sum_k phist[st][k][i])
__global__ void dsqk_kernel(const int* __restrict__ phist, float* __restrict__ dsq, int N) {
    int n = blockIdx.x * 256 + threadIdx.x;
    if (n >= N) return;
    int st = n >> SSH, i = n & (STILE - 1);
    const int* p = phist + (size_t)st * KCH_H * STILE + i;
    int s = 0;
#pragma unroll
    for (int k = 0; k < KCH_H; ++k) s += p[k * STILE];
    dsq[n] = sqrtf((float)s);
}

// ---------------------------------------------------------------------------
// K4: h2p[r][o] = dsq[r] * (x[r] @ Wc^T)[o].
// Wc in LDS (32KB); each wave processes 4 rows/iter.
// ---------------------------------------------------------------------------
__global__ __launch_bounds__(256) void h2_kernel(const float* __restrict__ x,
                                                 const float* __restrict__ WcG,
                                                 const float* __restrict__ dsq,
                                                 float* __restrict__ h2p, int N) {
    __shared__ float wl[16 * IN_C];
    for (int i = threadIdx.x; i < (16 * IN_C) / 4; i += 256)
        ((f32x4*)wl)[i] = ((const f32x4*)WcG)[i];
    __syncthreads();

    const int lane = threadIdx.x & 63;
    const int wid = (blockIdx.x * 256 + threadIdx.x) >> 6;
    const int nw  = (gridDim.x * 256) >> 6;

    for (int r0 = wid * 4; r0 < N; r0 += nw * 4) {
        const int rmax = min(4, N - r0);
        f32x4 a0[4], a1[4];
#pragma unroll
        for (int rr = 0; rr < 4; ++rr) {
            int r = r0 + (rr < rmax ? rr : 0);
            a0[rr] = *(const f32x4*)(x + (size_t)r * IN_C + 4 * lane);
            a1[rr] = *(const f32x4*)(x + (size_t)r * IN_C + 256 + 4 * lane);
        }
        float p[4][16];
#pragma unroll
        for (int oo = 0; oo < 16; ++oo) {
            f32x4 w0 = *(const f32x4*)(wl + oo * IN_C + 4 * lane);
            f32x4 w1 = *(const f32x4*)(wl + oo * IN_C + 256 + 4 * lane);
#pragma unroll
            for (int rr = 0; rr < 4; ++rr) {
                float s = a0[rr].x * w0.x;
                s = fmaf(a0[rr].y, w0.y, s);
                s = fmaf(a0[rr].z, w0.z, s);
                s = fmaf(a0[rr].w, w0.w, s);
                s = fmaf(a1[rr].x, w1.x, s);
                s = fmaf(a1[rr].y, w1.y, s);
                s = fmaf(a1[rr].z, w1.z, s);
                s = fmaf(a1[rr].w, w1.w, s);
                p[rr][oo] = s;
            }
        }
        float v[4];
#pragma unroll
        for (int rr = 0; rr < 4; ++rr) {
#define RSTEP(MASK, HALF)                                              \
            {                                                          \
                const bool hi = (lane & MASK) != 0;                    \
                _Pragma("unroll")                                      \
                for (int ii = 0; ii < HALF; ++ii) {                    \
                    float send = hi ? p[rr][ii] : p[rr][ii + HALF];    \
                    float recv = __shfl_xor(send, MASK, 64);           \
                    float keep = hi ? p[rr][ii + HALF] : p[rr][ii];    \
                    p[rr][ii] = keep + recv;                           \
                }                                                      \
            }
            RSTEP(1, 8)
            RSTEP(2, 4)
            RSTEP(4, 2)
            RSTEP(8, 1)
#undef RSTEP
            v[rr] = p[rr][0];
        }
        const bool h16 = (lane & 16) != 0;
        float sA = h16 ? v[0] : v[1];
        float mA = (h16 ? v[1] : v[0]) + __shfl_xor(sA, 16, 64);
        float sB = h16 ? v[2] : v[3];
        float mB = (h16 ? v[3] : v[2]) + __shfl_xor(sB, 16, 64);
        const bool h32 = (lane & 32) != 0;
        float sC = h32 ? mA : mB;
        float f  = (h32 ? mB : mA) + __shfl_xor(sC, 32, 64);
        const int qq = lane >> 4, jj = lane & 15;
        const int oo = ((jj & 1) << 3) | ((jj & 2) << 1) | ((jj & 4) >> 1) | ((jj & 8) >> 3);
        if (qq < rmax) {
            int r = r0 + qq;
            h2p[(size_t)r * OUT_C + oo] = f * dsq[r];
        }
    }
}

// K5: out[i] = cconst[i & 15]
__global__ void initout_kernel(const float* __restrict__ cconst,
                               float* __restrict__ out, int total) {
    int i = blockIdx.x * 256 + threadIdx.x;
    if (i < total) out[i] = cconst[i & 15];
}

// ---------------------------------------------------------------------------
// K6: edge scatter, 16 lanes/edge, one f32 global atomic per lane (proven
// R1 pattern). out is L2-resident (3.2 MB); h2p line per edge is 64B.
// ---------------------------------------------------------------------------
__global__ __launch_bounds__(256) void edge_kernel(const int* __restrict__ ei,
                                                   const float* __restrict__ dsq,
                                                   const float* __restrict__ h2p,
                                                   float* __restrict__ out, int E) {
    int t = blockIdx.x * 256 + threadIdx.x;
    int e = t >> 4;
    if (e >= E) return;
    int o = t & 15;
    int r = ei[e];
    int c = ei[E + e];
    float v = dsq[c] * h2p[(size_t)r * OUT_C + o];
    unsafeAtomicAdd(&out[(size_t)c * OUT_C + o], v);
}

// ---------------------------------------------------------------------------
extern "C" void kernel_launch(void* const* d_in, const int* in_sizes, int n_in,
                              void* d_out, int out_size, void* d_ws, size_t ws_size,
                              hipStream_t stream) {
    const float* x  = (const float*)d_in[0];
    const int*   ei = (const int*)d_in[1];
    const float* W1 = (const float*)d_in[2];
    const float* b1 = (const float*)d_in[3];
    const float* W2 = (const float*)d_in[4];
    const float* b2 = (const float*)d_in[5];
    float* out = (float*)d_out;

    const int N = in_sizes[0] / IN_C;    // 50000
    const int E = in_sizes[1] / 2;       // 800000
    const int ST = (N + STILE - 1) / STILE;      // 13

    // workspace (4-byte units):
    // Wc[8192] | cconst[16] | dsq[N] | h2p[16N] | phist[ST*KCH_H*STILE]
    float* ws     = (float*)d_ws;
    float* Wc     = ws;
    float* cconst = ws + 16 * IN_C;
    float* dsq    = cconst + 16;
    float* h2p    = dsq + N;
    int*   phist  = (int*)(h2p + (size_t)16 * N);
    // total ~ 8.6 MB

    hipLaunchKernelGGL(prep_kernel, dim3(33), dim3(256), 0, stream,
                       W1, b1, W2, b2, Wc, cconst);
    hipLaunchKernelGGL(hist_kernel, dim3(ST * KCH_H), dim3(256), 0, stream, ei, phist, E);
    hipLaunchKernelGGL(dsqk_kernel, dim3((N + 255) / 256), dim3(256), 0, stream, phist, dsq, N);
    hipLaunchKernelGGL(h2_kernel, dim3(768), dim3(256), 0, stream, x, Wc, dsq, h2p, N);
    hipLaunchKernelGGL(initout_kernel, dim3((out_size + 255) / 256), dim3(256), 0, stream,
                       cconst, out, out_size);
    hipLaunchKernelGGL(edge_kernel, dim3((E * 16 + 255) / 256), dim3(256), 0, stream,
                       ei, dsq, h2p, out, E);
}

// Round 11
// 102.541 us; speedup vs baseline: 2.7035x; 1.0231x over previous
//
#include <hip/hip_runtime.h>
#include <hip/hip_bf16.h>
#include <hip/hip_fp16.h>

#define IN_C 512
#define HID_C 128
#define OUT_C 16
#define STILE 8192     // nodes per hist supertile (32KB LDS)
#define SSH  13        // log2(STILE)
#define KCH_H 16       // edge chunks per supertile (hist)

typedef float    f32x4 __attribute__((ext_vector_type(4)));
typedef float    f32x2 __attribute__((ext_vector_type(2)));
typedef int      i32x4 __attribute__((ext_vector_type(4)));
typedef _Float16 h16x2 __attribute__((ext_vector_type(2)));

// Packed f16 global atomic add (global_atomic_pk_add_f16 on CDNA).
__device__ inline void pk_atomic_add_f16(h16x2* addr, h16x2 val) {
#if __has_builtin(__builtin_amdgcn_global_atomic_fadd_v2f16)
    __builtin_amdgcn_global_atomic_fadd_v2f16(addr, val);
#else
    unsigned int* ap = (unsigned int*)addr;
    unsigned int old = *ap, assumed;
    do {
        assumed = old;
        h16x2 cur = __builtin_bit_cast(h16x2, assumed);
        h16x2 nv = cur + val;
        old = atomicCAS(ap, assumed, __builtin_bit_cast(unsigned int, nv));
    } while (old != assumed);
#endif
}

// ---------------------------------------------------------------------------
// K1 (fused): blocks 0..31 -> Wc = W2@W1 (16x512); block 32 -> cconst;
// blocks 33.. -> supertile degree histogram (LDS-binned, no global atomics).
// ---------------------------------------------------------------------------
__global__ __launch_bounds__(256) void prep_hist_kernel(
        const float* __restrict__ W1, const float* __restrict__ b1,
        const float* __restrict__ W2, const float* __restrict__ b2,
        float* __restrict__ Wc, float* __restrict__ cconst,
        const int* __restrict__ ei, int* __restrict__ phist, int E) {
    __shared__ int h[STILE];
    if (blockIdx.x < 32) {
        int idx = blockIdx.x * 256 + threadIdx.x;   // 0 .. 8191
        int o = idx >> 9;
        int k = idx & 511;
        float s = 0.f;
#pragma unroll 8
        for (int hh = 0; hh < HID_C; ++hh)
            s = fmaf(W2[o * HID_C + hh], W1[hh * IN_C + k], s);
        Wc[o * IN_C + k] = s;
        return;
    }
    if (blockIdx.x == 32) {
        if (threadIdx.x < OUT_C) {
            int o = threadIdx.x;
            float s = b2[o];
            for (int hh = 0; hh < HID_C; ++hh)
                s = fmaf(b1[hh], W2[o * HID_C + hh], s);
            cconst[o] = s;
        }
        return;
    }
    const int hb = blockIdx.x - 33;
    const int st = hb / KCH_H;
    const int k = hb - st * KCH_H;
    for (int i = threadIdx.x; i < STILE; i += 256) h[i] = 0;
    __syncthreads();

    const int chunk = (((E + KCH_H - 1) / KCH_H) + 3) & ~3;
    const int beg = k * chunk;
    const int end = min(E, beg + chunk);
    const int* cols = ei + E;

    const int nv = (end > beg) ? ((end - beg) >> 2) : 0;
    const i32x4* cv = (const i32x4*)(cols + beg);
    for (int i = threadIdx.x; i < nv; i += 256) {
        i32x4 c = cv[i];
#pragma unroll
        for (int j = 0; j < 4; ++j) {
            int cj = c[j];
            if ((cj >> SSH) == st) atomicAdd(&h[cj & (STILE - 1)], 1);
        }
    }
    for (int e = beg + (nv << 2) + threadIdx.x; e < end; e += 256) {
        int cj = cols[e];
        if ((cj >> SSH) == st) atomicAdd(&h[cj & (STILE - 1)], 1);
    }
    __syncthreads();
    int* outp = phist + (size_t)hb * STILE;   // layout [st][k][i]
    for (int i = threadIdx.x; i < STILE; i += 256) outp[i] = h[i];
}

// ---------------------------------------------------------------------------
// K2 (fused): dsq[n] = sqrt(sum_k phist[st][k][i]); zero the f16 agg buffer.
// ---------------------------------------------------------------------------
__global__ void dsq_zero_kernel(const int* __restrict__ phist, float* __restrict__ dsq,
                                unsigned int* __restrict__ agg32, int N, int aggWords) {
    int i = blockIdx.x * 256 + threadIdx.x;
    if (i < N) {
        int st = i >> SSH, ii = i & (STILE - 1);
        const int* p = phist + (size_t)st * KCH_H * STILE + ii;
        int s = 0;
#pragma unroll
        for (int k = 0; k < KCH_H; ++k) s += p[k * STILE];
        dsq[i] = sqrtf((float)s);
    }
    if (i < aggWords) agg32[i] = 0u;
}

// ---------------------------------------------------------------------------
// K3: h2p[r][o] = dsq[r] * (x[r] @ Wc^T)[o].
// Wc in LDS (32KB); each wave processes 4 rows/iter.
// ---------------------------------------------------------------------------
__global__ __launch_bounds__(256) void h2_kernel(const float* __restrict__ x,
                                                 const float* __restrict__ WcG,
                                                 const float* __restrict__ dsq,
                                                 float* __restrict__ h2p, int N) {
    __shared__ float wl[16 * IN_C];
    for (int i = threadIdx.x; i < (16 * IN_C) / 4; i += 256)
        ((f32x4*)wl)[i] = ((const f32x4*)WcG)[i];
    __syncthreads();

    const int lane = threadIdx.x & 63;
    const int wid = (blockIdx.x * 256 + threadIdx.x) >> 6;
    const int nw  = (gridDim.x * 256) >> 6;

    for (int r0 = wid * 4; r0 < N; r0 += nw * 4) {
        const int rmax = min(4, N - r0);
        f32x4 a0[4], a1[4];
#pragma unroll
        for (int rr = 0; rr < 4; ++rr) {
            int r = r0 + (rr < rmax ? rr : 0);
            a0[rr] = *(const f32x4*)(x + (size_t)r * IN_C + 4 * lane);
            a1[rr] = *(const f32x4*)(x + (size_t)r * IN_C + 256 + 4 * lane);
        }
        float p[4][16];
#pragma unroll
        for (int oo = 0; oo < 16; ++oo) {
            f32x4 w0 = *(const f32x4*)(wl + oo * IN_C + 4 * lane);
            f32x4 w1 = *(const f32x4*)(wl + oo * IN_C + 256 + 4 * lane);
#pragma unroll
            for (int rr = 0; rr < 4; ++rr) {
                float s = a0[rr].x * w0.x;
                s = fmaf(a0[rr].y, w0.y, s);
                s = fmaf(a0[rr].z, w0.z, s);
                s = fmaf(a0[rr].w, w0.w, s);
                s = fmaf(a1[rr].x, w1.x, s);
                s = fmaf(a1[rr].y, w1.y, s);
                s = fmaf(a1[rr].z, w1.z, s);
                s = fmaf(a1[rr].w, w1.w, s);
                p[rr][oo] = s;
            }
        }
        float v[4];
#pragma unroll
        for (int rr = 0; rr < 4; ++rr) {
#define RSTEP(MASK, HALF)                                              \
            {                                                          \
                const bool hi = (lane & MASK) != 0;                    \
                _Pragma("unroll")                                      \
                for (int ii = 0; ii < HALF; ++ii) {                    \
                    float send = hi ? p[rr][ii] : p[rr][ii + HALF];    \
                    float recv = __shfl_xor(send, MASK, 64);           \
                    float keep = hi ? p[rr][ii + HALF] : p[rr][ii];    \
                    p[rr][ii] = keep + recv;                           \
                }                                                      \
            }
            RSTEP(1, 8)
            RSTEP(2, 4)
            RSTEP(4, 2)
            RSTEP(8, 1)
#undef RSTEP
            v[rr] = p[rr][0];
        }
        const bool h16 = (lane & 16) != 0;
        float sA = h16 ? v[0] : v[1];
        float mA = (h16 ? v[1] : v[0]) + __shfl_xor(sA, 16, 64);
        float sB = h16 ? v[2] : v[3];
        float mB = (h16 ? v[3] : v[2]) + __shfl_xor(sB, 16, 64);
        const bool h32 = (lane & 32) != 0;
        float sC = h32 ? mA : mB;
        float f  = (h32 ? mB : mA) + __shfl_xor(sC, 32, 64);
        const int qq = lane >> 4, jj = lane & 15;
        const int oo = ((jj & 1) << 3) | ((jj & 2) << 1) | ((jj & 4) >> 1) | ((jj & 8) >> 3);
        if (qq < rmax) {
            int r = r0 + qq;
            h2p[(size_t)r * OUT_C + oo] = f * dsq[r];
        }
    }
}

// ---------------------------------------------------------------------------
// K4: edge scatter with packed-f16 atomics. 8 lanes/edge; each lane adds
// 2 values via ONE global_atomic_pk_add_f16 -> 6.4M atomic ops (half of
// the f32-scalar version). agg accumulates unscaled sums of h2p[r];
// dsq[c] and cconst folded in at finalize.
// ---------------------------------------------------------------------------
__global__ __launch_bounds__(256) void edge_kernel(const int* __restrict__ ei,
                                                   const float* __restrict__ h2p,
                                                   h16x2* __restrict__ agg, int E) {
    int t = blockIdx.x * 256 + threadIdx.x;
    int e = t >> 3;
    if (e >= E) return;
    int op = t & 7;                       // half2 pair: outputs 2op, 2op+1
    int r = ei[e];
    int c = ei[E + e];
    f32x2 h = *(const f32x2*)(h2p + (size_t)r * OUT_C + (op << 1));
    h16x2 v;
    v.x = (_Float16)h.x;
    v.y = (_Float16)h.y;
    pk_atomic_add_f16(&agg[(size_t)c * 8 + op], v);
}

// ---------------------------------------------------------------------------
// K5: finalize: out[n][o] = cconst[o] + dsq[n] * (float)agg[n][o]
// One thread per h16x2 word (2 outputs), f32x2 store.
// ---------------------------------------------------------------------------
__global__ void final_kernel(const h16x2* __restrict__ agg, const float* __restrict__ dsq,
                             const float* __restrict__ cconst, float* __restrict__ out,
                             int words) {
    int i = blockIdx.x * 256 + threadIdx.x;
    if (i >= words) return;
    int n = i >> 3;
    int o = (i & 7) << 1;
    h16x2 a = agg[i];
    float d = dsq[n];
    f32x2 r;
    r.x = fmaf(d, (float)a.x, cconst[o]);
    r.y = fmaf(d, (float)a.y, cconst[o + 1]);
    *(f32x2*)(out + ((size_t)i << 1)) = r;
}

// ---------------------------------------------------------------------------
extern "C" void kernel_launch(void* const* d_in, const int* in_sizes, int n_in,
                              void* d_out, int out_size, void* d_ws, size_t ws_size,
                              hipStream_t stream) {
    const float* x  = (const float*)d_in[0];
    const int*   ei = (const int*)d_in[1];
    const float* W1 = (const float*)d_in[2];
    const float* b1 = (const float*)d_in[3];
    const float* W2 = (const float*)d_in[4];
    const float* b2 = (const float*)d_in[5];
    float* out = (float*)d_out;

    const int N = in_sizes[0] / IN_C;    // 50000
    const int E = in_sizes[1] / 2;       // 800000
    const int ST = (N + STILE - 1) / STILE;      // 7
    const int aggWords = (N * OUT_C) / 2;        // 400000 h16x2 words

    // workspace (4-byte units):
    // Wc[8192] | cconst[16] | dsq[N] | h2p[16N] | phist[ST*KCH_H*STILE] | agg[aggWords]
    float* ws     = (float*)d_ws;
    float* Wc     = ws;
    float* cconst = ws + 16 * IN_C;
    float* dsq    = cconst + 16;
    float* h2p    = dsq + N;
    int*   phist  = (int*)(h2p + (size_t)16 * N);
    unsigned int* agg32 = (unsigned int*)(phist + (size_t)ST * KCH_H * STILE);
    h16x2* agg = (h16x2*)agg32;
    // total ~ 9.3 MB

    hipLaunchKernelGGL(prep_hist_kernel, dim3(33 + ST * KCH_H), dim3(256), 0, stream,
                       W1, b1, W2, b2, Wc, cconst, ei, phist, E);
    hipLaunchKernelGGL(dsq_zero_kernel, dim3((aggWords + 255) / 256), dim3(256), 0, stream,
                       phist, dsq, agg32, N, aggWords);
    hipLaunchKernelGGL(h2_kernel, dim3(768), dim3(256), 0, stream, x, Wc, dsq, h2p, N);
    hipLaunchKernelGGL(edge_kernel, dim3((E * 8 + 255) / 256), dim3(256), 0, stream,
                       ei, h2p, agg, E);
    hipLaunchKernelGGL(final_kernel, dim3((aggWords + 255) / 256), dim3(256), 0, stream,
                       agg, dsq, cconst, out, aggWords);
}